// Round 3
// baseline (298.529 us; speedup 1.0000x reference)
//
#include <hip/hip_runtime.h>
#include <math.h>

// dims
#define B_   64
#define N1_  1152
#define P_   8
#define N2_  128
#define D_   16
#define ISPLIT 32
#define ICH  (N1_/ISPLIT)   // 36 i's per split (k1/k3c)
#define ICHA 18             // i's per block for k3a (grid.y = 64)

// ---------------------------------------------------------------------------
// K1: s0 partials.  s0p[split][b][n][d] = sum_{i in split, p} W[i,n,d,p]*x[b,i,p]
// block 256 = nl(16 n) x dg(2 -> 4 d) x bg(8 -> 8 b): per-thread 8b x 4d.
// grid (8, 32, 2): x = n-tile, y = i-split, z = d-half.  2 blocks/CU.
// FMA:LDS = 256 FMA : 128 B = 2:1.  W tile (16n x 8d x 8p) double-buffered.
// ---------------------------------------------------------------------------
__global__ __launch_bounds__(256) void k1_s0(const float* __restrict__ x,
                                             const float* __restrict__ W,
                                             float* __restrict__ s0p)
{
    __shared__ float Wl[2][16 * 68];          // 16 n x (64 + 4 pad) floats
    const int tid = threadIdx.x;
    const int n0  = blockIdx.x * 16;
    const int isp = blockIdx.y;
    const int i0  = isp * ICH;
    const int dz  = blockIdx.z;               // d-half: 0 or 1
    const int nl  = tid & 15;
    const int dg  = (tid >> 4) & 1;
    const int bg  = tid >> 5;                 // 0..7
    const int b0  = bg * 8;
    const int dbase = dg * 4;                 // d within the 8-d tile

    // staging: 256 float4 per tile, one per thread
    const int snn = tid >> 4, sr = tid & 15;  // n row, f4 within 64-float row

    float4 pf;
    {
        pf = *(const float4*)(W + ((size_t)i0 * N2_ + n0 + snn) * 128 + dz * 64 + sr * 4);
        *(float4*)&Wl[0][snn * 68 + sr * 4] = pf;
    }

    float acc[8][4];
#pragma unroll
    for (int a = 0; a < 8; ++a)
#pragma unroll
        for (int c = 0; c < 4; ++c) acc[a][c] = 0.f;

    for (int ii = 0; ii < ICH; ++ii) {
        const int i = i0 + ii;
        if (ii + 1 < ICH)
            pf = *(const float4*)(W + ((size_t)(i + 1) * N2_ + n0 + snn) * 128 + dz * 64 + sr * 4);
        __syncthreads();
        const float* Wb = Wl[ii & 1];

        float xr[8][8];
#pragma unroll
        for (int bb = 0; bb < 8; ++bb) {
            const float* xp = x + ((size_t)(b0 + bb) * N1_ + i) * P_;
            float4 a0 = *(const float4*)xp;
            float4 a1 = *(const float4*)(xp + 4);
            xr[bb][0] = a0.x; xr[bb][1] = a0.y; xr[bb][2] = a0.z; xr[bb][3] = a0.w;
            xr[bb][4] = a1.x; xr[bb][5] = a1.y; xr[bb][6] = a1.z; xr[bb][7] = a1.w;
        }
#pragma unroll
        for (int dd = 0; dd < 4; ++dd) {
            const float* wp = &Wb[nl * 68 + (dbase + dd) * 8];
            float4 w0 = *(const float4*)wp;
            float4 w1 = *(const float4*)(wp + 4);
#pragma unroll
            for (int bb = 0; bb < 8; ++bb) {
                float t = w0.x * xr[bb][0] + w0.y * xr[bb][1]
                        + w0.z * xr[bb][2] + w0.w * xr[bb][3]
                        + w1.x * xr[bb][4] + w1.y * xr[bb][5]
                        + w1.z * xr[bb][6] + w1.w * xr[bb][7];
                acc[bb][dd] += t;
            }
        }
        if (ii + 1 < ICH)
            *(float4*)&Wl[(ii + 1) & 1][snn * 68 + sr * 4] = pf;
    }
    // store: 4 consecutive d per thread -> one float4 per b
#pragma unroll
    for (int bb = 0; bb < 8; ++bb) {
        float4 v = make_float4(acc[bb][0], acc[bb][1], acc[bb][2], acc[bb][3]);
        *(float4*)(s0p + (size_t)isp * (B_ * N2_ * D_) + (size_t)(b0 + bb) * (N2_ * D_)
                   + (n0 + nl) * D_ + dz * 8 + dg * 4) = v;
    }
}

// ---------------------------------------------------------------------------
// K2/K4: reduce ISPLIT partials, scale, squash over d (16), write v.
// ---------------------------------------------------------------------------
__global__ __launch_bounds__(256) void k2_squash(const float* __restrict__ spart,
                                                 float* __restrict__ vout,
                                                 float scale)
{
    int idx = blockIdx.x * 256 + threadIdx.x;   // 0 .. 131071
    float s = 0.f;
    for (int sp = 0; sp < ISPLIT; ++sp)
        s += spart[(size_t)sp * (B_ * N2_ * D_) + idx];
    s *= scale;
    float sq = s * s;
    sq += __shfl_xor(sq, 1);
    sq += __shfl_xor(sq, 2);
    sq += __shfl_xor(sq, 4);
    sq += __shfl_xor(sq, 8);
    float norm = sqrtf(sq + 1.1920929e-7f);
    vout[idx] = (sq / (1.f + sq)) * (s / norm);
}

// ---------------------------------------------------------------------------
// K3a: raw[b][i][n] = sum_d v0[b,n,d] * (sum_p W[i,n,d,p]*x[b,i,p])
// block 256 = wv(4) x bg(8 -> 8 b) x dg(2 -> 8 d) x nlo(4); n = wv*4+nlo.
// lane bits: [5:3]=bg [2]=dg [1:0]=nlo -> dg halves combined by shfl_xor(.,4).
// grid (8, 64): x = n-tile(16), y = i-chunk(18).  2 blocks/CU.
// FMA:LDS = 512 FMA : 256 B = 2:1.
// ---------------------------------------------------------------------------
__global__ __launch_bounds__(256) void k3a_raw(const float* __restrict__ x,
                                               const float* __restrict__ W,
                                               const float* __restrict__ v0,
                                               float* __restrict__ raw)
{
    __shared__ float Wl[2][16 * 132];           // 16 n x (128 + 4 pad)
    const int tid = threadIdx.x;
    const int n0  = blockIdx.x * 16;
    const int i0  = blockIdx.y * ICHA;
    const int nlo = tid & 3;
    const int dg  = (tid >> 2) & 1;
    const int bg  = (tid >> 3) & 7;
    const int wv  = tid >> 6;
    const int n   = n0 + wv * 4 + nlo;
    const int b0  = bg * 8;
    const int d0  = dg * 8;

    // v0 fragment: 8 b x 8 d, held in registers for the whole i-loop
    float v0r[8][8];
#pragma unroll
    for (int bb = 0; bb < 8; ++bb) {
        const float* vp = v0 + (size_t)(b0 + bb) * (N2_ * D_) + n * D_ + d0;
        float4 q0 = *(const float4*)vp;
        float4 q1 = *(const float4*)(vp + 4);
        v0r[bb][0] = q0.x; v0r[bb][1] = q0.y; v0r[bb][2] = q0.z; v0r[bb][3] = q0.w;
        v0r[bb][4] = q1.x; v0r[bb][5] = q1.y; v0r[bb][6] = q1.z; v0r[bb][7] = q1.w;
    }

    // staging: 512 float4 per tile (16 n x 32 f4), 2 per thread
    const int st0 = tid, st1 = tid + 256;
    const int sn0 = st0 >> 5, sr0 = st0 & 31;
    const int sn1 = st1 >> 5, sr1 = st1 & 31;

    float4 pf0, pf1;
    {
        pf0 = *(const float4*)(W + ((size_t)i0 * N2_ + n0 + sn0) * 128 + sr0 * 4);
        pf1 = *(const float4*)(W + ((size_t)i0 * N2_ + n0 + sn1) * 128 + sr1 * 4);
        *(float4*)&Wl[0][sn0 * 132 + sr0 * 4] = pf0;
        *(float4*)&Wl[0][sn1 * 132 + sr1 * 4] = pf1;
    }

    for (int s = 0; s < ICHA; ++s) {
        const int i = i0 + s;
        if (s + 1 < ICHA) {
            pf0 = *(const float4*)(W + ((size_t)(i + 1) * N2_ + n0 + sn0) * 128 + sr0 * 4);
            pf1 = *(const float4*)(W + ((size_t)(i + 1) * N2_ + n0 + sn1) * 128 + sr1 * 4);
        }
        __syncthreads();
        const float* Wb = Wl[s & 1];

        float xr[8][8];
#pragma unroll
        for (int bb = 0; bb < 8; ++bb) {
            const float* xp = x + ((size_t)(b0 + bb) * N1_ + i) * P_;
            float4 a0 = *(const float4*)xp;
            float4 a1 = *(const float4*)(xp + 4);
            xr[bb][0] = a0.x; xr[bb][1] = a0.y; xr[bb][2] = a0.z; xr[bb][3] = a0.w;
            xr[bb][4] = a1.x; xr[bb][5] = a1.y; xr[bb][6] = a1.z; xr[bb][7] = a1.w;
        }
        float rawp[8] = {0.f, 0.f, 0.f, 0.f, 0.f, 0.f, 0.f, 0.f};
#pragma unroll
        for (int dd = 0; dd < 8; ++dd) {
            const float* wp = &Wb[(wv * 4 + nlo) * 132 + (d0 + dd) * 8];
            float4 w0 = *(const float4*)wp;
            float4 w1 = *(const float4*)(wp + 4);
#pragma unroll
            for (int bb = 0; bb < 8; ++bb) {
                float t = w0.x * xr[bb][0] + w0.y * xr[bb][1]
                        + w0.z * xr[bb][2] + w0.w * xr[bb][3]
                        + w1.x * xr[bb][4] + w1.y * xr[bb][5]
                        + w1.z * xr[bb][6] + w1.w * xr[bb][7];
                rawp[bb] += t * v0r[bb][dd];
            }
        }
        // combine the two d-halves (dg = lane bit 2)
#pragma unroll
        for (int bb = 0; bb < 8; ++bb)
            rawp[bb] += __shfl_xor(rawp[bb], 4);
        if (dg == 0) {
#pragma unroll
            for (int bb = 0; bb < 8; ++bb)
                raw[(size_t)(b0 + bb) * (N1_ * N2_) + (size_t)i * N2_ + n] = rawp[bb];
        }
        if (s + 1 < ICHA) {
            float* Wn = Wl[(s + 1) & 1];
            *(float4*)&Wn[sn0 * 132 + sr0 * 4] = pf0;
            *(float4*)&Wn[sn1 * 132 + sr1 * 4] = pf1;
        }
    }
}

// ---------------------------------------------------------------------------
// K3b: in-place softmax over n (128) per (b,i) row. one wave per row.
// ---------------------------------------------------------------------------
__global__ __launch_bounds__(256) void k3b_softmax(float* __restrict__ raw)
{
    int row  = blockIdx.x * 4 + (threadIdx.x >> 6);   // 0 .. 73727
    int lane = threadIdx.x & 63;
    float* rp = raw + (size_t)row * N2_;
    float a = rp[lane], b = rp[lane + 64];
    float m = fmaxf(a, b);
#pragma unroll
    for (int off = 32; off >= 1; off >>= 1) m = fmaxf(m, __shfl_xor(m, off));
    float e0 = __expf(a - m), e1 = __expf(b - m);
    float ssum = e0 + e1;
#pragma unroll
    for (int off = 32; off >= 1; off >>= 1) ssum += __shfl_xor(ssum, off);
    float inv = 1.f / ssum;
    rp[lane] = e0 * inv;
    rp[lane + 64] = e1 * inv;
}

// ---------------------------------------------------------------------------
// K3c: s1 partials.  s1p[split][b][n][d] = sum_{i in split} c[b,i,n]*pred[b,i,n,d]
// identical blocking to K1 plus the c weight.
// ---------------------------------------------------------------------------
__global__ __launch_bounds__(256) void k3c_s1(const float* __restrict__ x,
                                              const float* __restrict__ W,
                                              const float* __restrict__ cmat,
                                              float* __restrict__ s1p)
{
    __shared__ float Wl[2][16 * 68];
    const int tid = threadIdx.x;
    const int n0  = blockIdx.x * 16;
    const int isp = blockIdx.y;
    const int i0  = isp * ICH;
    const int dz  = blockIdx.z;
    const int nl  = tid & 15;
    const int dg  = (tid >> 4) & 1;
    const int bg  = tid >> 5;
    const int b0  = bg * 8;
    const int dbase = dg * 4;

    const int snn = tid >> 4, sr = tid & 15;

    float4 pf;
    {
        pf = *(const float4*)(W + ((size_t)i0 * N2_ + n0 + snn) * 128 + dz * 64 + sr * 4);
        *(float4*)&Wl[0][snn * 68 + sr * 4] = pf;
    }

    float acc[8][4];
#pragma unroll
    for (int a = 0; a < 8; ++a)
#pragma unroll
        for (int c = 0; c < 4; ++c) acc[a][c] = 0.f;

    for (int ii = 0; ii < ICH; ++ii) {
        const int i = i0 + ii;
        if (ii + 1 < ICH)
            pf = *(const float4*)(W + ((size_t)(i + 1) * N2_ + n0 + snn) * 128 + dz * 64 + sr * 4);
        __syncthreads();
        const float* Wb = Wl[ii & 1];

        float xr[8][8];
        float cr[8];
#pragma unroll
        for (int bb = 0; bb < 8; ++bb) {
            const float* xp = x + ((size_t)(b0 + bb) * N1_ + i) * P_;
            float4 a0 = *(const float4*)xp;
            float4 a1 = *(const float4*)(xp + 4);
            xr[bb][0] = a0.x; xr[bb][1] = a0.y; xr[bb][2] = a0.z; xr[bb][3] = a0.w;
            xr[bb][4] = a1.x; xr[bb][5] = a1.y; xr[bb][6] = a1.z; xr[bb][7] = a1.w;
            cr[bb] = cmat[(size_t)(b0 + bb) * (N1_ * N2_) + (size_t)i * N2_ + n0 + nl];
        }
#pragma unroll
        for (int dd = 0; dd < 4; ++dd) {
            const float* wp = &Wb[nl * 68 + (dbase + dd) * 8];
            float4 w0 = *(const float4*)wp;
            float4 w1 = *(const float4*)(wp + 4);
#pragma unroll
            for (int bb = 0; bb < 8; ++bb) {
                float t = w0.x * xr[bb][0] + w0.y * xr[bb][1]
                        + w0.z * xr[bb][2] + w0.w * xr[bb][3]
                        + w1.x * xr[bb][4] + w1.y * xr[bb][5]
                        + w1.z * xr[bb][6] + w1.w * xr[bb][7];
                acc[bb][dd] += cr[bb] * t;
            }
        }
        if (ii + 1 < ICH)
            *(float4*)&Wl[(ii + 1) & 1][snn * 68 + sr * 4] = pf;
    }
#pragma unroll
    for (int bb = 0; bb < 8; ++bb) {
        float4 v = make_float4(acc[bb][0], acc[bb][1], acc[bb][2], acc[bb][3]);
        *(float4*)(s1p + (size_t)isp * (B_ * N2_ * D_) + (size_t)(b0 + bb) * (N2_ * D_)
                   + (n0 + nl) * D_ + dz * 8 + dg * 4) = v;
    }
}

// ---------------------------------------------------------------------------
extern "C" void kernel_launch(void* const* d_in, const int* in_sizes, int n_in,
                              void* d_out, int out_size, void* d_ws, size_t ws_size,
                              hipStream_t stream)
{
    const float* x = (const float*)d_in[0];   // [64,1152,8]
    const float* W = (const float*)d_in[1];   // [1152,128,16,8]
    float* out = (float*)d_out;               // [64,128,16]

    float* s_part = (float*)d_ws;                              // 32*131072 floats (16 MB)
    float* v0     = s_part + (size_t)ISPLIT * B_ * N2_ * D_;   // 131072 floats
    float* raw    = v0 + B_ * N2_ * D_;                        // 9437184 floats (38 MB)

    k1_s0      <<<dim3(8, 32, 2), 256, 0, stream>>>(x, W, s_part);
    k2_squash  <<<512,            256, 0, stream>>>(s_part, v0, 1.f / 128.f);
    k3a_raw    <<<dim3(8, 64),    256, 0, stream>>>(x, W, v0, raw);
    k3b_softmax<<<18432,          256, 0, stream>>>(raw);
    k3c_s1     <<<dim3(8, 32, 2), 256, 0, stream>>>(x, W, raw, s_part);
    k2_squash  <<<512,            256, 0, stream>>>(s_part, out, 1.f);
}

// Round 4
// 252.208 us; speedup vs baseline: 1.1837x; 1.1837x over previous
//
#include <hip/hip_runtime.h>
#include <math.h>

// dims
#define B_   64
#define N1_  1152
#define P_   8
#define N2_  128
#define D_   16

// k1 (MFMA) decomposition
#define K1SPLIT 16            // i-splits -> partials
#define K1NGRP  32            // n-groups of 4
#define K1IB    (N1_ / K1SPLIT / 4)   // 18 i-blocks of 4 i per chunk

// k3c / k3a decomposition
#define ISPLIT 32
#define ICH  (N1_/ISPLIT)     // 36
#define ICHA 18

typedef __attribute__((ext_vector_type(8))) short bf16x8;
typedef __attribute__((ext_vector_type(4))) float f32x4;

// split 8 fp32 into hi/lo bf16 fragments (hi = truncate, lo = bf16(w - hi))
__device__ inline void split_frag(float4 a0, float4 a1, bf16x8& hi, bf16x8& lo)
{
    float w[8] = {a0.x, a0.y, a0.z, a0.w, a1.x, a1.y, a1.z, a1.w};
#pragma unroll
    for (int j = 0; j < 8; ++j) {
        unsigned ub = __float_as_uint(w[j]);
        hi[j] = (short)(ub >> 16);
        float hif = __uint_as_float(ub & 0xffff0000u);
        float r = w[j] - hif;
        lo[j] = (short)(__float_as_uint(r) >> 16);
    }
}

// ---------------------------------------------------------------------------
// K1 (MFMA): s0 partials. s0p[isp][b][n][d] = sum_{i in chunk, p} W[i,n,d,p]*x[b,i,p]
// One MFMA 16x16x32: M=d(16), N=b-tile(16), K=(4 i)x(8 p).
// A-lane (m=lane&15=d, quad=lane>>4=isub): W[i0+quad, n, d, 0..7] - contiguous.
// B-lane (col=lane&15=b, quad=isub):       x[b, i0+quad, 0..7]     - contiguous.
// Split-bf16 3-product per i-block keeps fp32-grade precision.
// block = 4 waves = 4 b-tiles (64 b). grid (32 n-grp x 16 i-split) = 512 blocks.
// No LDS, no barriers: loads pipeline freely against the MFMA chain.
// ---------------------------------------------------------------------------
__global__ __launch_bounds__(256) void k1_s0_mfma(const float* __restrict__ x,
                                                  const float* __restrict__ W,
                                                  float* __restrict__ s0p)
{
    const int tid   = threadIdx.x;
    const int lane  = tid & 63;
    const int wv    = tid >> 6;           // b-tile
    const int col   = lane & 15;          // b within tile (B), d row (A)
    const int quad  = lane >> 4;          // isub within i-block
    const int b     = wv * 16 + col;
    const int nbase = blockIdx.x * 4;
    const int isp   = blockIdx.y;
    const int ibase = isp * (N1_ / K1SPLIT);   // 72 i per chunk

    f32x4 acc[4];
#pragma unroll
    for (int nn = 0; nn < 4; ++nn) acc[nn] = (f32x4){0.f, 0.f, 0.f, 0.f};

    const float* xlane = x + ((size_t)b * N1_ + ibase + quad) * P_;

    for (int ib = 0; ib < K1IB; ++ib) {
        const int i0 = ibase + ib * 4;
        // B fragment (x) - shared across the 4 n's below
        float4 xa = *(const float4*)(xlane);
        float4 xb = *(const float4*)(xlane + 4);
        xlane += 4 * P_;
        bf16x8 bhi, blo;
        split_frag(xa, xb, bhi, blo);
#pragma unroll
        for (int nn = 0; nn < 4; ++nn) {
            const float* wp = W + (((size_t)(i0 + quad) * N2_ + nbase + nn) * D_ + col) * P_;
            float4 wa = *(const float4*)wp;
            float4 wb = *(const float4*)(wp + 4);
            bf16x8 ahi, alo;
            split_frag(wa, wb, ahi, alo);
            acc[nn] = __builtin_amdgcn_mfma_f32_16x16x32_bf16(ahi, bhi, acc[nn], 0, 0, 0);
            acc[nn] = __builtin_amdgcn_mfma_f32_16x16x32_bf16(ahi, blo, acc[nn], 0, 0, 0);
            acc[nn] = __builtin_amdgcn_mfma_f32_16x16x32_bf16(alo, bhi, acc[nn], 0, 0, 0);
        }
    }
    // C/D layout: col=lane&15 (b), row=(lane>>4)*4+reg (d) -> one float4 per n
#pragma unroll
    for (int nn = 0; nn < 4; ++nn) {
        float4 v = make_float4(acc[nn][0], acc[nn][1], acc[nn][2], acc[nn][3]);
        *(float4*)(s0p + (size_t)isp * (B_ * N2_ * D_) + (size_t)b * (N2_ * D_)
                   + (nbase + nn) * D_ + quad * 4) = v;
    }
}

// ---------------------------------------------------------------------------
// K2/K4: reduce nsplit partials, scale, squash over d (16), write v.
// ---------------------------------------------------------------------------
__global__ __launch_bounds__(256) void k2_squash(const float* __restrict__ spart,
                                                 float* __restrict__ vout,
                                                 float scale, int nsplit)
{
    int idx = blockIdx.x * 256 + threadIdx.x;   // 0 .. 131071
    float s = 0.f;
    for (int sp = 0; sp < nsplit; ++sp)
        s += spart[(size_t)sp * (B_ * N2_ * D_) + idx];
    s *= scale;
    float sq = s * s;
    sq += __shfl_xor(sq, 1);
    sq += __shfl_xor(sq, 2);
    sq += __shfl_xor(sq, 4);
    sq += __shfl_xor(sq, 8);
    float norm = sqrtf(sq + 1.1920929e-7f);
    vout[idx] = (sq / (1.f + sq)) * (s / norm);
}

// ---------------------------------------------------------------------------
// K3a: raw[b][i][n] = sum_d v0[b,n,d] * (sum_p W[i,n,d,p]*x[b,i,p])
// (unchanged from round 3: its LDS aliasing is 2-way = free)
// ---------------------------------------------------------------------------
__global__ __launch_bounds__(256) void k3a_raw(const float* __restrict__ x,
                                               const float* __restrict__ W,
                                               const float* __restrict__ v0,
                                               float* __restrict__ raw)
{
    __shared__ float Wl[2][16 * 132];           // 16 n x (128 + 4 pad)
    const int tid = threadIdx.x;
    const int n0  = blockIdx.x * 16;
    const int i0  = blockIdx.y * ICHA;
    const int nlo = tid & 3;
    const int dg  = (tid >> 2) & 1;
    const int bg  = (tid >> 3) & 7;
    const int wv  = tid >> 6;
    const int n   = n0 + wv * 4 + nlo;
    const int b0  = bg * 8;
    const int d0  = dg * 8;

    float v0r[8][8];
#pragma unroll
    for (int bb = 0; bb < 8; ++bb) {
        const float* vp = v0 + (size_t)(b0 + bb) * (N2_ * D_) + n * D_ + d0;
        float4 q0 = *(const float4*)vp;
        float4 q1 = *(const float4*)(vp + 4);
        v0r[bb][0] = q0.x; v0r[bb][1] = q0.y; v0r[bb][2] = q0.z; v0r[bb][3] = q0.w;
        v0r[bb][4] = q1.x; v0r[bb][5] = q1.y; v0r[bb][6] = q1.z; v0r[bb][7] = q1.w;
    }

    const int st0 = tid, st1 = tid + 256;
    const int sn0 = st0 >> 5, sr0 = st0 & 31;
    const int sn1 = st1 >> 5, sr1 = st1 & 31;

    float4 pf0, pf1;
    {
        pf0 = *(const float4*)(W + ((size_t)i0 * N2_ + n0 + sn0) * 128 + sr0 * 4);
        pf1 = *(const float4*)(W + ((size_t)i0 * N2_ + n0 + sn1) * 128 + sr1 * 4);
        *(float4*)&Wl[0][sn0 * 132 + sr0 * 4] = pf0;
        *(float4*)&Wl[0][sn1 * 132 + sr1 * 4] = pf1;
    }

    for (int s = 0; s < ICHA; ++s) {
        const int i = i0 + s;
        if (s + 1 < ICHA) {
            pf0 = *(const float4*)(W + ((size_t)(i + 1) * N2_ + n0 + sn0) * 128 + sr0 * 4);
            pf1 = *(const float4*)(W + ((size_t)(i + 1) * N2_ + n0 + sn1) * 128 + sr1 * 4);
        }
        __syncthreads();
        const float* Wb = Wl[s & 1];

        float xr[8][8];
#pragma unroll
        for (int bb = 0; bb < 8; ++bb) {
            const float* xp = x + ((size_t)(b0 + bb) * N1_ + i) * P_;
            float4 a0 = *(const float4*)xp;
            float4 a1 = *(const float4*)(xp + 4);
            xr[bb][0] = a0.x; xr[bb][1] = a0.y; xr[bb][2] = a0.z; xr[bb][3] = a0.w;
            xr[bb][4] = a1.x; xr[bb][5] = a1.y; xr[bb][6] = a1.z; xr[bb][7] = a1.w;
        }
        float rawp[8] = {0.f, 0.f, 0.f, 0.f, 0.f, 0.f, 0.f, 0.f};
#pragma unroll
        for (int dd = 0; dd < 8; ++dd) {
            const float* wp = &Wb[(wv * 4 + nlo) * 132 + (d0 + dd) * 8];
            float4 w0 = *(const float4*)wp;
            float4 w1 = *(const float4*)(wp + 4);
#pragma unroll
            for (int bb = 0; bb < 8; ++bb) {
                float t = w0.x * xr[bb][0] + w0.y * xr[bb][1]
                        + w0.z * xr[bb][2] + w0.w * xr[bb][3]
                        + w1.x * xr[bb][4] + w1.y * xr[bb][5]
                        + w1.z * xr[bb][6] + w1.w * xr[bb][7];
                rawp[bb] += t * v0r[bb][dd];
            }
        }
#pragma unroll
        for (int bb = 0; bb < 8; ++bb)
            rawp[bb] += __shfl_xor(rawp[bb], 4);
        if (dg == 0) {
#pragma unroll
            for (int bb = 0; bb < 8; ++bb)
                raw[(size_t)(b0 + bb) * (N1_ * N2_) + (size_t)i * N2_ + n] = rawp[bb];
        }
        if (s + 1 < ICHA) {
            float* Wn = Wl[(s + 1) & 1];
            *(float4*)&Wn[sn0 * 132 + sr0 * 4] = pf0;
            *(float4*)&Wn[sn1 * 132 + sr1 * 4] = pf1;
        }
    }
}

// ---------------------------------------------------------------------------
// K3b: in-place softmax over n (128) per (b,i) row. one wave per row.
// ---------------------------------------------------------------------------
__global__ __launch_bounds__(256) void k3b_softmax(float* __restrict__ raw)
{
    int row  = blockIdx.x * 4 + (threadIdx.x >> 6);   // 0 .. 73727
    int lane = threadIdx.x & 63;
    float* rp = raw + (size_t)row * N2_;
    float a = rp[lane], b = rp[lane + 64];
    float m = fmaxf(a, b);
#pragma unroll
    for (int off = 32; off >= 1; off >>= 1) m = fmaxf(m, __shfl_xor(m, off));
    float e0 = __expf(a - m), e1 = __expf(b - m);
    float ssum = e0 + e1;
#pragma unroll
    for (int off = 32; off >= 1; off >>= 1) ssum += __shfl_xor(ssum, off);
    float inv = 1.f / ssum;
    rp[lane] = e0 * inv;
    rp[lane + 64] = e1 * inv;
}

// ---------------------------------------------------------------------------
// K3c: s1p[isp][b][n][d] = sum_{i in split} c[b,i,n]*pred[b,i,n,d]
// Lane-bit fix vs round 3: within a half-wave only nl varies the LDS address
// (2-way alias = free). dg moved to bit 6; bg = (bit7)*4 + bits[5:4].
// ---------------------------------------------------------------------------
__global__ __launch_bounds__(256) void k3c_s1(const float* __restrict__ x,
                                              const float* __restrict__ W,
                                              const float* __restrict__ cmat,
                                              float* __restrict__ s1p)
{
    __shared__ float Wl[2][16 * 68];
    const int tid = threadIdx.x;
    const int n0  = blockIdx.x * 16;
    const int isp = blockIdx.y;
    const int i0  = isp * ICH;
    const int dz  = blockIdx.z;
    const int nl  = tid & 15;
    const int bglo = (tid >> 4) & 3;
    const int dg   = (tid >> 6) & 1;
    const int bghi = tid >> 7;
    const int bg   = bghi * 4 + bglo;
    const int b0  = bg * 8;
    const int dbase = dg * 4;

    const int snn = tid >> 4, sr = tid & 15;

    float4 pf;
    {
        pf = *(const float4*)(W + ((size_t)i0 * N2_ + n0 + snn) * 128 + dz * 64 + sr * 4);
        *(float4*)&Wl[0][snn * 68 + sr * 4] = pf;
    }

    float acc[8][4];
#pragma unroll
    for (int a = 0; a < 8; ++a)
#pragma unroll
        for (int c = 0; c < 4; ++c) acc[a][c] = 0.f;

    for (int ii = 0; ii < ICH; ++ii) {
        const int i = i0 + ii;
        if (ii + 1 < ICH)
            pf = *(const float4*)(W + ((size_t)(i + 1) * N2_ + n0 + snn) * 128 + dz * 64 + sr * 4);
        __syncthreads();
        const float* Wb = Wl[ii & 1];

        float xr[8][8];
        float cr[8];
#pragma unroll
        for (int bb = 0; bb < 8; ++bb) {
            const float* xp = x + ((size_t)(b0 + bb) * N1_ + i) * P_;
            float4 a0 = *(const float4*)xp;
            float4 a1 = *(const float4*)(xp + 4);
            xr[bb][0] = a0.x; xr[bb][1] = a0.y; xr[bb][2] = a0.z; xr[bb][3] = a0.w;
            xr[bb][4] = a1.x; xr[bb][5] = a1.y; xr[bb][6] = a1.z; xr[bb][7] = a1.w;
            cr[bb] = cmat[(size_t)(b0 + bb) * (N1_ * N2_) + (size_t)i * N2_ + n0 + nl];
        }
#pragma unroll
        for (int dd = 0; dd < 4; ++dd) {
            const float* wp = &Wb[nl * 68 + (dbase + dd) * 8];
            float4 w0 = *(const float4*)wp;
            float4 w1 = *(const float4*)(wp + 4);
#pragma unroll
            for (int bb = 0; bb < 8; ++bb) {
                float t = w0.x * xr[bb][0] + w0.y * xr[bb][1]
                        + w0.z * xr[bb][2] + w0.w * xr[bb][3]
                        + w1.x * xr[bb][4] + w1.y * xr[bb][5]
                        + w1.z * xr[bb][6] + w1.w * xr[bb][7];
                acc[bb][dd] += cr[bb] * t;
            }
        }
        if (ii + 1 < ICH)
            *(float4*)&Wl[(ii + 1) & 1][snn * 68 + sr * 4] = pf;
    }
#pragma unroll
    for (int bb = 0; bb < 8; ++bb) {
        float4 v = make_float4(acc[bb][0], acc[bb][1], acc[bb][2], acc[bb][3]);
        *(float4*)(s1p + (size_t)isp * (B_ * N2_ * D_) + (size_t)(b0 + bb) * (N2_ * D_)
                   + (n0 + nl) * D_ + dz * 8 + dg * 4) = v;
    }
}

// ---------------------------------------------------------------------------
extern "C" void kernel_launch(void* const* d_in, const int* in_sizes, int n_in,
                              void* d_out, int out_size, void* d_ws, size_t ws_size,
                              hipStream_t stream)
{
    const float* x = (const float*)d_in[0];   // [64,1152,8]
    const float* W = (const float*)d_in[1];   // [1152,128,16,8]
    float* out = (float*)d_out;               // [64,128,16]

    float* s_part = (float*)d_ws;                              // 32*131072 floats (16 MB)
    float* v0     = s_part + (size_t)ISPLIT * B_ * N2_ * D_;   // 131072 floats
    float* raw    = v0 + B_ * N2_ * D_;                        // 9437184 floats (38 MB)

    k1_s0_mfma <<<dim3(K1NGRP, K1SPLIT), 256, 0, stream>>>(x, W, s_part);
    k2_squash  <<<512,            256, 0, stream>>>(s_part, v0, 1.f / 128.f, K1SPLIT);
    k3a_raw    <<<dim3(8, 64),    256, 0, stream>>>(x, W, v0, raw);
    k3b_softmax<<<18432,          256, 0, stream>>>(raw);
    k3c_s1     <<<dim3(8, 32, 2), 256, 0, stream>>>(x, W, raw, s_part);
    k2_squash  <<<512,            256, 0, stream>>>(s_part, out, 1.f, ISPLIT);
}